// Round 2
// baseline (674.092 us; speedup 1.0000x reference)
//
#include <hip/hip_runtime.h>
#include <stdint.h>

// StraightThroughSubsetSampler: out = khot(top_k(scores/tau + gumbel_noise, k))
// Forward value of khot + soft - stop_grad(soft) == khot (+ ~1e-7 residue).
//
// One block (256 thr) per row. Radix-select over sortable-u32 keys:
//   pass0: 10-bit digit, 1024-bin LDS histogram (plain atomics),
//   compact candidates sharing the winning digit into a small LDS list,
//   passes 1-3 (8/8/6 bits) run on the compacted list (~1 elem/thread).
// Scans are wave-shuffle based (2 syncs/pass). Ties at the k boundary are
// resolved lowest-index-first via a rare block-uniform register-side path.

namespace {

constexpr int kN = 8192;        // row length
constexpr int kThreads = 256;   // 4 waves
constexpr int kVPT = kN / (kThreads * 4);  // 8 float4 per thread
constexpr int kEPT = kN / kThreads;        // 32 elements per thread
constexpr int kBins0 = 1024;    // 10-bit first digit
constexpr uint32_t kCap = 1024; // candidate list capacity

typedef float f32x4 __attribute__((ext_vector_type(4)));

__device__ __forceinline__ uint32_t f2sortable(float x) {
  uint32_t b = __float_as_uint(x);
  // monotonic float->uint: larger float => larger uint
  return (b & 0x80000000u) ? ~b : (b | 0x80000000u);
}

__global__ __launch_bounds__(kThreads, 8) void st_topk_khot(
    const float* __restrict__ scores, const float* __restrict__ noise,
    const float* __restrict__ tau_p, const int* __restrict__ k_p,
    float* __restrict__ out) {
  __shared__ __align__(16) uint32_t hist[kBins0];  // 4 KiB, reused all passes
  __shared__ uint32_t clist[kCap];                 // 4 KiB candidate keys
  __shared__ uint32_t wsum[4];
  __shared__ uint32_t bcast[3];                    // prefix / desired / eq
  __shared__ uint32_t cnt;

  const int t = threadIdx.x;
  const int lane = t & 63;
  const int w = t >> 6;
  const size_t row = blockIdx.x;
  const float tau = tau_p[0];
  const uint32_t k = (uint32_t)k_p[0];

  const float4* s4 = reinterpret_cast<const float4*>(scores + row * (size_t)kN);
  const float4* g4 = reinterpret_cast<const float4*>(noise + row * (size_t)kN);

  uint32_t u[kEPT];

  // ---- load, compute keys (bit-exact vs reference: div, then add) ----
#pragma unroll
  for (int i = 0; i < kVPT; ++i) {
    const int vi = i * kThreads + t;
    float4 s = s4[vi];
    float4 g = g4[vi];
    u[i * 4 + 0] = f2sortable(s.x / tau + g.x);
    u[i * 4 + 1] = f2sortable(s.y / tau + g.y);
    u[i * 4 + 2] = f2sortable(s.z / tau + g.z);
    u[i * 4 + 3] = f2sortable(s.w / tau + g.w);
  }

  // ---- pass 0: 1024-bin histogram of top-10-bit digit ----
  reinterpret_cast<uint4*>(hist)[t] = uint4{0u, 0u, 0u, 0u};
  if (t == 0) cnt = 0u;
  __syncthreads();
#pragma unroll
  for (int e = 0; e < kEPT; ++e) atomicAdd(&hist[u[e] >> 22], 1u);
  __syncthreads();

  uint32_t prefix, desired, eqn;

  {  // pass-0 scan: 4 bins/thread, suffix (descending-digit) counts
    uint4 hv = reinterpret_cast<const uint4*>(hist)[t];
    const uint32_t l0 = hv.x, l1 = hv.y, l2 = hv.z, l3 = hv.w;
    const uint32_t lsum = l0 + l1 + l2 + l3;
    uint32_t inc = lsum;  // inclusive suffix over lanes
#pragma unroll
    for (int off = 1; off < 64; off <<= 1) {
      const uint32_t o = __shfl_down(inc, off);
      if (lane + off < 64) inc += o;
    }
    if (lane == 0) wsum[w] = inc;
    __syncthreads();
    uint32_t hi = 0;
#pragma unroll
    for (int ww = 0; ww < 4; ++ww)
      if (ww > w) hi += wsum[ww];
    const uint32_t S = hi + (inc - lsum);  // elems in bins > 4t+3
    const uint32_t c3 = S + l3, c2 = c3 + l2, c1 = c2 + l1, c0 = c1 + l0;
    const uint32_t cums[4] = {c0, c1, c2, c3};
    const uint32_t nxts[4] = {c1, c2, c3, S};
    const uint32_t lv[4] = {l0, l1, l2, l3};
#pragma unroll
    for (int e = 0; e < 4; ++e) {
      if (cums[e] >= k && nxts[e] < k) {  // unique winner
        bcast[0] = (uint32_t)(4 * t + e) << 22;
        bcast[1] = k - nxts[e];
        bcast[2] = lv[e];
      }
    }
  }
  __syncthreads();
  prefix = bcast[0];
  desired = bcast[1];
  eqn = bcast[2];

  // ---- compact candidates matching the winning 10-bit digit ----
#pragma unroll
  for (int e = 0; e < kEPT; ++e) {
    if ((u[e] & 0xFFC00000u) == prefix) {
      const uint32_t pos = atomicAdd(&cnt, 1u);
      if (pos < kCap) clist[pos] = u[e];
    }
  }
  __syncthreads();
  const uint32_t m = cnt;
  const bool ovf = (m > kCap);  // block-uniform; rare (massive duplicate keys)
  uint32_t pmask = 0xFFC00000u;

  // ---- passes 1..3 on the compacted list (8 / 8 / 6 bits) ----
  const int shifts[3] = {14, 6, 0};
  const uint32_t dmasks[3] = {255u, 255u, 63u};
#pragma unroll
  for (int p = 0; p < 3; ++p) {
    const int shift = shifts[p];
    const uint32_t dmask = dmasks[p];
    hist[t] = 0u;
    __syncthreads();
    if (!ovf) {
      for (uint32_t idx = t; idx < m; idx += kThreads) {
        const uint32_t key = clist[idx];
        if ((key & pmask) == prefix) atomicAdd(&hist[(key >> shift) & dmask], 1u);
      }
    } else {
#pragma unroll
      for (int e = 0; e < kEPT; ++e)
        if ((u[e] & pmask) == prefix) atomicAdd(&hist[(u[e] >> shift) & dmask], 1u);
    }
    __syncthreads();
    const uint32_t lsum = hist[t];
    uint32_t inc = lsum;
#pragma unroll
    for (int off = 1; off < 64; off <<= 1) {
      const uint32_t o = __shfl_down(inc, off);
      if (lane + off < 64) inc += o;
    }
    if (lane == 0) wsum[w] = inc;
    __syncthreads();
    uint32_t hi = 0;
#pragma unroll
    for (int ww = 0; ww < 4; ++ww)
      if (ww > w) hi += wsum[ww];
    const uint32_t S = hi + (inc - lsum);
    const uint32_t cum = S + lsum;
    if (cum >= desired && S < desired) {
      bcast[0] = prefix | ((uint32_t)t << shift);
      bcast[1] = desired - S;
      bcast[2] = lsum;
    }
    __syncthreads();
    prefix = bcast[0];
    desired = bcast[1];
    eqn = bcast[2];
    pmask |= dmask << shift;
    __syncthreads();  // protect bcast readers from next pass's winner write
  }

  const uint32_t thr = prefix;  // exact key of the kth largest
  f32x4* o4 = reinterpret_cast<f32x4*>(out + row * (size_t)kN);

  if (eqn == desired) {
    // ---- fast path: no boundary tie; >= compare ----
#pragma unroll
    for (int i = 0; i < kVPT; ++i) {
      f32x4 o;
      o.x = (u[i * 4 + 0] >= thr) ? 1.0f : 0.0f;
      o.y = (u[i * 4 + 1] >= thr) ? 1.0f : 0.0f;
      o.z = (u[i * 4 + 2] >= thr) ? 1.0f : 0.0f;
      o.w = (u[i * 4 + 3] >= thr) ? 1.0f : 0.0f;
      __builtin_nontemporal_store(o, o4 + (i * kThreads + t));
    }
  } else {
    // ---- rare block-uniform path: ties straddle k; keep lowest indices ----
    // element u[i*4+c] has global index i*1024 + t*4 + c (ascending in i,t,c)
    uint32_t keep = 0u;
    uint32_t base = 0u;
#pragma unroll
    for (int i = 0; i < kVPT; ++i) {
      const uint32_t f0 = (u[i * 4 + 0] == thr) ? 1u : 0u;
      const uint32_t f1 = (u[i * 4 + 1] == thr) ? 1u : 0u;
      const uint32_t f2 = (u[i * 4 + 2] == thr) ? 1u : 0u;
      const uint32_t f3 = (u[i * 4 + 3] == thr) ? 1u : 0u;
      const uint32_t lc = f0 + f1 + f2 + f3;
      uint32_t pf = lc;  // inclusive prefix over lanes (ascending)
#pragma unroll
      for (int off = 1; off < 64; off <<= 1) {
        const uint32_t o = __shfl_up(pf, off);
        if (lane >= off) pf += o;
      }
      if (lane == 63) wsum[w] = pf;
      __syncthreads();
      uint32_t lower = 0, total = 0;
#pragma unroll
      for (int ww = 0; ww < 4; ++ww) {
        const uint32_t v = wsum[ww];
        total += v;
        if (ww < w) lower += v;
      }
      uint32_t r = base + lower + (pf - lc);  // rank of first equal here
      if (f0) { if (r < desired) keep |= 1u << (i * 4 + 0); ++r; }
      if (f1) { if (r < desired) keep |= 1u << (i * 4 + 1); ++r; }
      if (f2) { if (r < desired) keep |= 1u << (i * 4 + 2); ++r; }
      if (f3) { if (r < desired) keep |= 1u << (i * 4 + 3); ++r; }
      base += total;
      __syncthreads();  // wsum reused next group
    }
#pragma unroll
    for (int i = 0; i < kVPT; ++i) {
      f32x4 o;
      o.x = (u[i * 4 + 0] > thr || (u[i * 4 + 0] == thr && ((keep >> (i * 4 + 0)) & 1u))) ? 1.0f : 0.0f;
      o.y = (u[i * 4 + 1] > thr || (u[i * 4 + 1] == thr && ((keep >> (i * 4 + 1)) & 1u))) ? 1.0f : 0.0f;
      o.z = (u[i * 4 + 2] > thr || (u[i * 4 + 2] == thr && ((keep >> (i * 4 + 2)) & 1u))) ? 1.0f : 0.0f;
      o.w = (u[i * 4 + 3] > thr || (u[i * 4 + 3] == thr && ((keep >> (i * 4 + 3)) & 1u))) ? 1.0f : 0.0f;
      __builtin_nontemporal_store(o, o4 + (i * kThreads + t));
    }
  }
}

}  // namespace

extern "C" void kernel_launch(void* const* d_in, const int* in_sizes, int n_in,
                              void* d_out, int out_size, void* d_ws, size_t ws_size,
                              hipStream_t stream) {
  (void)in_sizes;
  (void)n_in;
  (void)d_ws;
  (void)ws_size;
  (void)out_size;
  const float* scores = (const float*)d_in[0];
  const float* noise = (const float*)d_in[1];
  const float* tau_p = (const float*)d_in[2];
  const int* k_p = (const int*)d_in[3];
  float* out = (float*)d_out;

  hipLaunchKernelGGL(st_topk_khot, dim3(kN), dim3(kThreads), 0, stream,
                     scores, noise, tau_p, k_p, out);
}